// Round 11
// baseline (325.924 us; speedup 1.0000x reference)
//
#include <hip/hip_runtime.h>
#include <hip/hip_bf16.h>

#define N_NODES 50000
#define N_EDGES 600000
#define DIM 128
#define EPS 1e-5f

#define NPB 64                                   // nodes per gemm tile
#define GEMM_GRID ((N_NODES + NPB - 1) / NPB)    // 782
#define HIST_BLOCKS 512
#define NSLICE 8                                 // channel slices -> XCDs
#define GPB 256                                  // gather blocks per slice
#define SCAN_P 200                               // csr kernel blocks (co-resident)

// ---------------- K1: gemm layer-1 + histogram (independent work) ----------
// s_sliced[slice][n][16ch]: slice-major, 3.2 MB per slice (per-XCD L2-resident)
__device__ __forceinline__ void gemm_body(
    const float* __restrict__ xin, const float* __restrict__ W,
    const float* __restrict__ bias, const float* __restrict__ tptr,
    float4* __restrict__ s_sliced, int tile, float xs[NPB][DIM])
{
    const int tid = threadIdx.x;
    const int nb = tile * NPB;
    const float4* xin4 = (const float4*)xin;
#pragma unroll
    for (int i = 0; i < 8; ++i) {
        int f4 = tid + i * 256;
        int nl = f4 >> 5;
        int q  = f4 & 31;
        int node = nb + nl;
        float4 v = make_float4(0.f, 0.f, 0.f, 0.f);
        if (node < N_NODES) v = xin4[(size_t)node * 32 + q];
        *(float4*)&xs[nl][q * 4] = v;
    }
    __syncthreads();

    const int quad = tid & 31;
    const int dq   = quad * 4;
    const int nloc = (tid >> 5) * 8;
    const int slice = quad >> 2;
    const int qin   = quad & 3;

    float4 acc[8];
#pragma unroll
    for (int i = 0; i < 8; ++i) acc[i] = make_float4(0.f, 0.f, 0.f, 0.f);

    for (int k = 0; k < DIM; k += 4) {
        float4 w0 = *(const float4*)&W[(k + 1) * DIM + dq];
        float4 w1 = *(const float4*)&W[(k + 2) * DIM + dq];
        float4 w2 = *(const float4*)&W[(k + 3) * DIM + dq];
        float4 w3 = *(const float4*)&W[(k + 4) * DIM + dq];
#pragma unroll
        for (int i = 0; i < 8; ++i) {
            float4 xv = *(const float4*)&xs[nloc + i][k];
            acc[i].x = fmaf(xv.x, w0.x, fmaf(xv.y, w1.x, fmaf(xv.z, w2.x, fmaf(xv.w, w3.x, acc[i].x))));
            acc[i].y = fmaf(xv.x, w0.y, fmaf(xv.y, w1.y, fmaf(xv.z, w2.y, fmaf(xv.w, w3.y, acc[i].y))));
            acc[i].z = fmaf(xv.x, w0.z, fmaf(xv.y, w1.z, fmaf(xv.z, w2.z, fmaf(xv.w, w3.z, acc[i].z))));
            acc[i].w = fmaf(xv.x, w0.w, fmaf(xv.y, w1.w, fmaf(xv.z, w2.w, fmaf(xv.w, w3.w, acc[i].w))));
        }
    }

    const float tval = *tptr;
    float4 w0r = *(const float4*)&W[dq];
    float4 bb  = *(const float4*)&bias[dq];
    const size_t sbase = (size_t)slice * N_NODES * 4 + qin;
#pragma unroll
    for (int i = 0; i < 8; ++i) {
        int node = nb + nloc + i;
        if (node < N_NODES) {
            float4 r;
            r.x = acc[i].x + tval * w0r.x + bb.x;
            r.y = acc[i].y + tval * w0r.y + bb.y;
            r.z = acc[i].z + tval * w0r.z + bb.z;
            r.w = acc[i].w + tval * w0r.w + bb.w;
            s_sliced[sbase + (size_t)node * 4] = r;
        }
    }
}

__global__ __launch_bounds__(256) void gemm_hist_kernel(
    const float* __restrict__ xin, const float* __restrict__ W,
    const float* __restrict__ bias, const float* __restrict__ tptr,
    float4* __restrict__ s_sliced,
    const int* __restrict__ tgt, int* __restrict__ cursor)
{
    __shared__ float xs[NPB][DIM];     // 32 KB (hist blocks leave it unused)
    if (blockIdx.x < GEMM_GRID) {
        gemm_body(xin, W, bias, tptr, s_sliced, blockIdx.x, xs);
    } else {
        int e = (blockIdx.x - GEMM_GRID) * 256 + threadIdx.x;
        for (; e < N_EDGES; e += HIST_BLOCKS * 256)
            atomicAdd(&cursor[tgt[e]], 1);
    }
}

// plain gemm (layer 2)
__global__ __launch_bounds__(256) void gemm_kernel(
    const float* __restrict__ xin, const float* __restrict__ W,
    const float* __restrict__ bias, const float* __restrict__ tptr,
    float4* __restrict__ s_sliced)
{
    __shared__ float xs[NPB][DIM];
    gemm_body(xin, W, bias, tptr, s_sliced, blockIdx.x, xs);
}

// ---------------- K2: scan + rowptr + place, single kernel -----------------
// SCAN_P=200 blocks x 256 thr: all co-resident on 256 CUs -> spin-safe.
// flags[0]=ticket1 flags[1]=flag1 flags[2]=ticket2 flags[3]=flag2 (pre-zeroed)
__global__ __launch_bounds__(256) void csr_kernel(
    const int* __restrict__ src, const int* __restrict__ tgt,
    int* __restrict__ cursor /* counts in, zero out */,
    int* __restrict__ rowptr, int* __restrict__ bsum, int* __restrict__ bsum2,
    int* __restrict__ flags, int* __restrict__ eid)
{
    __shared__ int ish[256];
    __shared__ int amILast;
    __shared__ int sbase;
    const int tid = threadIdx.x;
    const int b = blockIdx.x;
    const int n4 = N_NODES / 4;                  // 12500

    int idx4 = b * 256 + tid;
    int4 c = make_int4(0, 0, 0, 0);
    if (idx4 < n4) c = ((const int4*)cursor)[idx4];
    int tsum = c.x + c.y + c.z + c.w;

    // block-wide inclusive scan of tsum
    ish[tid] = tsum;
    __syncthreads();
#pragma unroll
    for (int off = 1; off < 256; off <<= 1) {
        int v = (tid >= off) ? ish[tid - off] : 0;
        __syncthreads();
        ish[tid] += v;
        __syncthreads();
    }
    int incl = ish[tid];
    int btot = ish[255];

    if (tid == 0) {
        bsum[b] = btot;
        __threadfence();
        amILast = (atomicAdd(&flags[0], 1) == SCAN_P - 1);
    }
    __syncthreads();

    if (amILast) {                               // last block scans the 200 sums
        __threadfence();
        int v = (tid < SCAN_P) ? atomicAdd(&bsum[tid], 0) : 0;
        ish[tid] = v;
        __syncthreads();
#pragma unroll
        for (int off = 1; off < 256; off <<= 1) {
            int u = (tid >= off) ? ish[tid - off] : 0;
            __syncthreads();
            ish[tid] += u;
            __syncthreads();
        }
        if (tid < SCAN_P) bsum2[tid] = ish[tid] - v;   // exclusive
        __threadfence();
        if (tid == 0) atomicExch(&flags[1], 1);
    }

    if (tid == 0) {
        while (atomicAdd(&flags[1], 0) == 0) __builtin_amdgcn_s_sleep(2);
        __threadfence();
        sbase = atomicAdd(&bsum2[b], 0);
    }
    __syncthreads();

    int base = sbase + incl - tsum;              // exclusive prefix for my int4
    if (idx4 < n4) {
        int4 r;
        r.x = base;
        r.y = base + c.x;
        r.z = r.y + c.y;
        r.w = r.z + c.z;
        ((int4*)rowptr)[idx4] = r;
        if (idx4 == n4 - 1) rowptr[N_NODES] = r.w + c.w;
    }

    // barrier 2: rowptr complete everywhere before place
    __threadfence();
    __syncthreads();
    if (tid == 0) {
        if (atomicAdd(&flags[2], 1) == SCAN_P - 1) {
            __threadfence();
            atomicExch(&flags[3], 1);
        }
        while (atomicAdd(&flags[3], 0) == 0) __builtin_amdgcn_s_sleep(2);
    }
    __syncthreads();
    __threadfence();

    // place: edge-parallel, cursor counts -> 0
    for (int e = b * 256 + tid; e < N_EDGES; e += SCAN_P * 256) {
        int tg = tgt[e];
        int idx = atomicSub(&cursor[tg], 1) - 1;
        eid[rowptr[tg] + idx] = src[e];
    }
}

// ---------------- gather + relu + groupnorm (XCD-sliced, node-parallel) ----
__global__ __launch_bounds__(256) void gather_gn_kernel(
    const float4* __restrict__ s_sliced, const int* __restrict__ rowptr,
    const int* __restrict__ eid,
    const float* __restrict__ gamma, const float* __restrict__ beta,
    float* __restrict__ out, int N)
{
    const int slice = blockIdx.x & 7;
    const int sblk  = blockIdx.x >> 3;
    const int wave  = threadIdx.x >> 6;
    const int lane  = threadIdx.x & 63;
    const int nslot = lane >> 2;
    const int qin   = lane & 3;

    const float4* stab = s_sliced + (size_t)slice * N_NODES * 4;
    const int gch = slice * 16 + qin * 4;
    const float4 gm = *(const float4*)&gamma[gch];
    const float4 bt = *(const float4*)&beta[gch];

    const int wslot0  = sblk * 4 + wave;
    const int nwslots = GPB * 4;

    for (int base = wslot0 * 16; base < N; base += nwslots * 16) {
        int node = base + nslot;
        bool valid = node < N;
        int beg = 0, end = 0;
        if (valid) {
            beg = rowptr[node];
            end = rowptr[node + 1];
        }

        float4 acc = make_float4(0.f, 0.f, 0.f, 0.f);
        int e = beg;
        for (; e + 3 < end; e += 4) {
            int s0 = eid[e];
            int s1 = eid[e + 1];
            int s2 = eid[e + 2];
            int s3 = eid[e + 3];
            float4 v0 = stab[(size_t)s0 * 4 + qin];
            float4 v1 = stab[(size_t)s1 * 4 + qin];
            float4 v2 = stab[(size_t)s2 * 4 + qin];
            float4 v3 = stab[(size_t)s3 * 4 + qin];
            acc.x += (v0.x + v1.x) + (v2.x + v3.x);
            acc.y += (v0.y + v1.y) + (v2.y + v3.y);
            acc.z += (v0.z + v1.z) + (v2.z + v3.z);
            acc.w += (v0.w + v1.w) + (v2.w + v3.w);
        }
        for (; e < end; ++e) {
            int s = eid[e];
            float4 v = stab[(size_t)s * 4 + qin];
            acc.x += v.x;
            acc.y += v.y;
            acc.z += v.z;
            acc.w += v.w;
        }

        if (valid) {
            int deg = end - beg;
            float inv = (deg > 0) ? (1.0f / (float)deg) : 0.0f;
            float ax = fmaxf(acc.x * inv, 0.f);
            float ay = fmaxf(acc.y * inv, 0.f);
            float az = fmaxf(acc.z * inv, 0.f);
            float aw = fmaxf(acc.w * inv, 0.f);
            float mu = 0.25f * (ax + ay + az + aw);
            float dx = ax - mu, dy = ay - mu, dz = az - mu, dw = aw - mu;
            float var = 0.25f * (dx * dx + dy * dy + dz * dz + dw * dw);
            float rs = rsqrtf(var + EPS);
            float4 r;
            r.x = dx * rs * gm.x + bt.x;
            r.y = dy * rs * gm.y + bt.y;
            r.z = dz * rs * gm.z + bt.z;
            r.w = dw * rs * gm.w + bt.w;
            *(float4*)&out[(size_t)node * DIM + gch] = r;
        }
    }
}

extern "C" void kernel_launch(void* const* d_in, const int* in_sizes, int n_in,
                              void* d_out, int out_size, void* d_ws, size_t ws_size,
                              hipStream_t stream) {
    const float* t      = (const float*)d_in[0];
    const float* x      = (const float*)d_in[1];
    const int*   src    = (const int*)d_in[2];
    const int*   tgt    = (const int*)d_in[3];
    const float* W1     = (const float*)d_in[5];
    const float* b1     = (const float*)d_in[6];
    const float* W2     = (const float*)d_in[7];
    const float* b2     = (const float*)d_in[8];
    const float* gamma1 = (const float*)d_in[9];
    const float* beta1  = (const float*)d_in[10];
    const float* gamma2 = (const float*)d_in[11];
    const float* beta2  = (const float*)d_in[12];
    float* out = (float*)d_out;

    const size_t NODE_BYTES = (size_t)N_NODES * DIM * sizeof(float);  // 25.6 MB
    char* ws = (char*)d_ws;
    size_t off = 0;
    float4* s_sliced = (float4*)(ws + off); off += NODE_BYTES;
    int*    rowptr   = (int*)(ws + off);    off += ((size_t)N_NODES + 4) * 4;
    off = (off + 255) & ~(size_t)255;
    int*    cursor   = (int*)(ws + off);    off += ((size_t)N_NODES + 64) * 4;  // counts + flags
    int*    flags    = cursor + N_NODES;    // flags[0..3], pre-zeroed by memset
    off = (off + 255) & ~(size_t)255;
    int*    bsum     = (int*)(ws + off);    off += 256 * 4;
    int*    bsum2    = (int*)(ws + off);    off += 256 * 4;
    off = (off + 255) & ~(size_t)255;
    int*    eid      = (int*)(ws + off);    off += (size_t)N_EDGES * 4;

    const int gather_grid = NSLICE * GPB;   // 2048

    // 1) zero counts + flags
    hipMemsetAsync(cursor, 0, ((size_t)N_NODES + 64) * 4, stream);
    // 2) gemm layer-1 + histogram (independent, merged)
    gemm_hist_kernel<<<GEMM_GRID + HIST_BLOCKS, 256, 0, stream>>>(
        x, W1, b1, t, s_sliced, tgt, cursor);
    // 3) scan + rowptr + place (single kernel, co-resident spin barriers)
    csr_kernel<<<SCAN_P, 256, 0, stream>>>(src, tgt, cursor, rowptr, bsum, bsum2, flags, eid);
    // 4) gather+GN layer-1  (h lives in d_out)
    gather_gn_kernel<<<gather_grid, 256, 0, stream>>>(s_sliced, rowptr, eid, gamma1, beta1, out, N_NODES);
    // 5) gemm layer-2
    gemm_kernel<<<GEMM_GRID, 256, 0, stream>>>(out, W2, b2, t, s_sliced);
    // 6) gather+GN layer-2
    gather_gn_kernel<<<gather_grid, 256, 0, stream>>>(s_sliced, rowptr, eid, gamma2, beta2, out, N_NODES);
}

// Round 12
// 291.688 us; speedup vs baseline: 1.1174x; 1.1174x over previous
//
#include <hip/hip_runtime.h>
#include <hip/hip_bf16.h>

#define N_NODES 50000
#define N_EDGES 600000
#define DIM 128
#define EPS 1e-5f

#define NPB 64                                   // nodes per gemm tile
#define GEMM_GRID ((N_NODES + NPB - 1) / NPB)    // 782
#define HIST_BLOCKS 512
#define NSLICE 8                                 // channel slices -> XCDs
#define GPB 256                                  // gather blocks per slice
#define SCAN_NB 49                               // ceil(50000/1024)

// s_sliced[slice][n][16ch]: slice-major, 3.2 MB per slice (per-XCD L2-resident)
__device__ __forceinline__ void gemm_body(
    const float* __restrict__ xin, const float* __restrict__ W,
    const float* __restrict__ bias, const float* __restrict__ tptr,
    float4* __restrict__ s_sliced, int tile, float xs[NPB][DIM])
{
    const int tid = threadIdx.x;
    const int nb = tile * NPB;
    const float4* xin4 = (const float4*)xin;
#pragma unroll
    for (int i = 0; i < 8; ++i) {
        int f4 = tid + i * 256;
        int nl = f4 >> 5;
        int q  = f4 & 31;
        int node = nb + nl;
        float4 v = make_float4(0.f, 0.f, 0.f, 0.f);
        if (node < N_NODES) v = xin4[(size_t)node * 32 + q];
        *(float4*)&xs[nl][q * 4] = v;
    }
    __syncthreads();

    const int quad = tid & 31;
    const int dq   = quad * 4;
    const int nloc = (tid >> 5) * 8;
    const int slice = quad >> 2;
    const int qin   = quad & 3;

    float4 acc[8];
#pragma unroll
    for (int i = 0; i < 8; ++i) acc[i] = make_float4(0.f, 0.f, 0.f, 0.f);

    for (int k = 0; k < DIM; k += 4) {
        float4 w0 = *(const float4*)&W[(k + 1) * DIM + dq];
        float4 w1 = *(const float4*)&W[(k + 2) * DIM + dq];
        float4 w2 = *(const float4*)&W[(k + 3) * DIM + dq];
        float4 w3 = *(const float4*)&W[(k + 4) * DIM + dq];
#pragma unroll
        for (int i = 0; i < 8; ++i) {
            float4 xv = *(const float4*)&xs[nloc + i][k];
            acc[i].x = fmaf(xv.x, w0.x, fmaf(xv.y, w1.x, fmaf(xv.z, w2.x, fmaf(xv.w, w3.x, acc[i].x))));
            acc[i].y = fmaf(xv.x, w0.y, fmaf(xv.y, w1.y, fmaf(xv.z, w2.y, fmaf(xv.w, w3.y, acc[i].y))));
            acc[i].z = fmaf(xv.x, w0.z, fmaf(xv.y, w1.z, fmaf(xv.z, w2.z, fmaf(xv.w, w3.z, acc[i].z))));
            acc[i].w = fmaf(xv.x, w0.w, fmaf(xv.y, w1.w, fmaf(xv.z, w2.w, fmaf(xv.w, w3.w, acc[i].w))));
        }
    }

    const float tval = *tptr;
    float4 w0r = *(const float4*)&W[dq];
    float4 bb  = *(const float4*)&bias[dq];
    const size_t sbase = (size_t)slice * N_NODES * 4 + qin;
#pragma unroll
    for (int i = 0; i < 8; ++i) {
        int node = nb + nloc + i;
        if (node < N_NODES) {
            float4 r;
            r.x = acc[i].x + tval * w0r.x + bb.x;
            r.y = acc[i].y + tval * w0r.y + bb.y;
            r.z = acc[i].z + tval * w0r.z + bb.z;
            r.w = acc[i].w + tval * w0r.w + bb.w;
            s_sliced[sbase + (size_t)node * 4] = r;
        }
    }
}

// gemm layer-1 + histogram (independent work, merged dispatch)
__global__ __launch_bounds__(256) void gemm_hist_kernel(
    const float* __restrict__ xin, const float* __restrict__ W,
    const float* __restrict__ bias, const float* __restrict__ tptr,
    float4* __restrict__ s_sliced,
    const int* __restrict__ tgt, int* __restrict__ cursor)
{
    __shared__ float xs[NPB][DIM];     // 32 KB (hist blocks leave it unused)
    if (blockIdx.x < GEMM_GRID) {
        gemm_body(xin, W, bias, tptr, s_sliced, blockIdx.x, xs);
    } else {
        int e = (blockIdx.x - GEMM_GRID) * 256 + threadIdx.x;
        for (; e < N_EDGES; e += HIST_BLOCKS * 256)
            atomicAdd(&cursor[tgt[e]], 1);
    }
}

__global__ __launch_bounds__(256) void gemm_kernel(
    const float* __restrict__ xin, const float* __restrict__ W,
    const float* __restrict__ bias, const float* __restrict__ tptr,
    float4* __restrict__ s_sliced)
{
    __shared__ float xs[NPB][DIM];
    gemm_body(xin, W, bias, tptr, s_sliced, blockIdx.x, xs);
}

// merged scan (pass1 + bsum-scan + rowptr write), 49 blocks — all co-resident.
// flags[0]=ticket, flags[1]=bsum2-ready (pre-zeroed by memset)
__global__ __launch_bounds__(256) void scan_kernel(
    const int* __restrict__ counts, int* __restrict__ bsum,
    int* __restrict__ bsum2, int* __restrict__ flags,
    int* __restrict__ rowptr)
{
    __shared__ int sh[256];
    __shared__ int amILast;
    __shared__ int sbase;
    const int tid = threadIdx.x;
    const int b = blockIdx.x;
    const int n4 = N_NODES / 4;                  // 12500

    int idx4 = b * 256 + tid;
    int4 c = make_int4(0, 0, 0, 0);
    if (idx4 < n4) c = ((const int4*)counts)[idx4];
    int tsum = c.x + c.y + c.z + c.w;

    // block-wide inclusive scan
    sh[tid] = tsum;
    __syncthreads();
#pragma unroll
    for (int off = 1; off < 256; off <<= 1) {
        int v = (tid >= off) ? sh[tid - off] : 0;
        __syncthreads();
        sh[tid] += v;
        __syncthreads();
    }
    int incl = sh[tid];

    if (tid == 0) {
        atomicExch(&bsum[b], sh[255]);           // device-scope publish
        amILast = (atomicAdd(&flags[0], 1) == SCAN_NB - 1);
    }
    __syncthreads();

    if (amILast) {
        if (tid < 64) {                          // one wave scans 49 sums
            int v = (tid < SCAN_NB) ? atomicAdd(&bsum[tid], 0) : 0;
            int incl2 = v;
#pragma unroll
            for (int off = 1; off < 64; off <<= 1) {
                int u = __shfl_up(incl2, off);
                if ((threadIdx.x & 63) >= off) incl2 += u;
            }
            if (tid < SCAN_NB) atomicExch(&bsum2[tid], incl2 - v);   // exclusive
        }
        __syncthreads();
        if (tid == 0) atomicExch(&flags[1], 1);
    }

    if (tid == 0) {
        while (atomicAdd(&flags[1], 0) == 0) __builtin_amdgcn_s_sleep(2);
        sbase = atomicAdd(&bsum2[b], 0);
    }
    __syncthreads();

    int base = sbase + incl - tsum;              // exclusive prefix for my int4
    if (idx4 < n4) {
        int4 r;
        r.x = base;
        r.y = base + c.x;
        r.z = r.y + c.y;
        r.w = r.z + c.z;
        ((int4*)rowptr)[idx4] = r;
        if (idx4 == n4 - 1) rowptr[N_NODES] = r.w + c.w;
    }
}

__global__ __launch_bounds__(256) void place_kernel(
    const int* __restrict__ src, const int* __restrict__ tgt,
    const int* __restrict__ rowptr,
    int* __restrict__ cursor, int* __restrict__ eid, int E)
{
    int e = blockIdx.x * 256 + threadIdx.x;
    if (e >= E) return;
    int t = tgt[e];
    int idx = atomicSub(&cursor[t], 1) - 1;
    eid[rowptr[t] + idx] = src[e];
}

// gather + relu + groupnorm (XCD-sliced, node-parallel lanes)
__global__ __launch_bounds__(256) void gather_gn_kernel(
    const float4* __restrict__ s_sliced, const int* __restrict__ rowptr,
    const int* __restrict__ eid,
    const float* __restrict__ gamma, const float* __restrict__ beta,
    float* __restrict__ out, int N)
{
    const int slice = blockIdx.x & 7;
    const int sblk  = blockIdx.x >> 3;
    const int wave  = threadIdx.x >> 6;
    const int lane  = threadIdx.x & 63;
    const int nslot = lane >> 2;
    const int qin   = lane & 3;

    const float4* stab = s_sliced + (size_t)slice * N_NODES * 4;
    const int gch = slice * 16 + qin * 4;
    const float4 gm = *(const float4*)&gamma[gch];
    const float4 bt = *(const float4*)&beta[gch];

    const int wslot0  = sblk * 4 + wave;
    const int nwslots = GPB * 4;

    for (int base = wslot0 * 16; base < N; base += nwslots * 16) {
        int node = base + nslot;
        bool valid = node < N;
        int beg = 0, end = 0;
        if (valid) {
            beg = rowptr[node];
            end = rowptr[node + 1];
        }

        float4 acc = make_float4(0.f, 0.f, 0.f, 0.f);
        int e = beg;
        for (; e + 3 < end; e += 4) {
            int s0 = eid[e];
            int s1 = eid[e + 1];
            int s2 = eid[e + 2];
            int s3 = eid[e + 3];
            float4 v0 = stab[(size_t)s0 * 4 + qin];
            float4 v1 = stab[(size_t)s1 * 4 + qin];
            float4 v2 = stab[(size_t)s2 * 4 + qin];
            float4 v3 = stab[(size_t)s3 * 4 + qin];
            acc.x += (v0.x + v1.x) + (v2.x + v3.x);
            acc.y += (v0.y + v1.y) + (v2.y + v3.y);
            acc.z += (v0.z + v1.z) + (v2.z + v3.z);
            acc.w += (v0.w + v1.w) + (v2.w + v3.w);
        }
        for (; e < end; ++e) {
            int s = eid[e];
            float4 v = stab[(size_t)s * 4 + qin];
            acc.x += v.x;
            acc.y += v.y;
            acc.z += v.z;
            acc.w += v.w;
        }

        if (valid) {
            int deg = end - beg;
            float inv = (deg > 0) ? (1.0f / (float)deg) : 0.0f;
            float ax = fmaxf(acc.x * inv, 0.f);
            float ay = fmaxf(acc.y * inv, 0.f);
            float az = fmaxf(acc.z * inv, 0.f);
            float aw = fmaxf(acc.w * inv, 0.f);
            float mu = 0.25f * (ax + ay + az + aw);
            float dx = ax - mu, dy = ay - mu, dz = az - mu, dw = aw - mu;
            float var = 0.25f * (dx * dx + dy * dy + dz * dz + dw * dw);
            float rs = rsqrtf(var + EPS);
            float4 r;
            r.x = dx * rs * gm.x + bt.x;
            r.y = dy * rs * gm.y + bt.y;
            r.z = dz * rs * gm.z + bt.z;
            r.w = dw * rs * gm.w + bt.w;
            *(float4*)&out[(size_t)node * DIM + gch] = r;
        }
    }
}

extern "C" void kernel_launch(void* const* d_in, const int* in_sizes, int n_in,
                              void* d_out, int out_size, void* d_ws, size_t ws_size,
                              hipStream_t stream) {
    const float* t      = (const float*)d_in[0];
    const float* x      = (const float*)d_in[1];
    const int*   src    = (const int*)d_in[2];
    const int*   tgt    = (const int*)d_in[3];
    const float* W1     = (const float*)d_in[5];
    const float* b1     = (const float*)d_in[6];
    const float* W2     = (const float*)d_in[7];
    const float* b2     = (const float*)d_in[8];
    const float* gamma1 = (const float*)d_in[9];
    const float* beta1  = (const float*)d_in[10];
    const float* gamma2 = (const float*)d_in[11];
    const float* beta2  = (const float*)d_in[12];
    float* out = (float*)d_out;

    const size_t NODE_BYTES = (size_t)N_NODES * DIM * sizeof(float);  // 25.6 MB
    char* ws = (char*)d_ws;
    size_t off = 0;
    float4* s_sliced = (float4*)(ws + off); off += NODE_BYTES;
    int*    rowptr   = (int*)(ws + off);    off += ((size_t)N_NODES + 4) * 4;
    off = (off + 255) & ~(size_t)255;
    int*    cursor   = (int*)(ws + off);    off += ((size_t)N_NODES + 64) * 4;  // counts + flags
    int*    flags    = cursor + N_NODES;    // flags[0..1], pre-zeroed by memset
    off = (off + 255) & ~(size_t)255;
    int*    bsum     = (int*)(ws + off);    off += 64 * 4;
    int*    bsum2    = (int*)(ws + off);    off += 64 * 4;
    off = (off + 255) & ~(size_t)255;
    int*    eid      = (int*)(ws + off);    off += (size_t)N_EDGES * 4;

    const int edge_grid   = (N_EDGES + 255) / 256;     // 2344
    const int gather_grid = NSLICE * GPB;              // 2048

    // 1) zero counts + flags
    hipMemsetAsync(cursor, 0, ((size_t)N_NODES + 64) * 4, stream);
    // 2) gemm layer-1 + histogram (independent, merged)
    gemm_hist_kernel<<<GEMM_GRID + HIST_BLOCKS, 256, 0, stream>>>(
        x, W1, b1, t, s_sliced, tgt, cursor);
    // 3) scan (pass1 + bsum + rowptr merged; 49 co-resident blocks)
    scan_kernel<<<SCAN_NB, 256, 0, stream>>>(cursor, bsum, bsum2, flags, rowptr);
    // 4) place (full edge-parallel grid)
    place_kernel<<<edge_grid, 256, 0, stream>>>(src, tgt, rowptr, cursor, eid, N_EDGES);
    // 5) gather+GN layer-1  (h lives in d_out)
    gather_gn_kernel<<<gather_grid, 256, 0, stream>>>(s_sliced, rowptr, eid, gamma1, beta1, out, N_NODES);
    // 6) gemm layer-2
    gemm_kernel<<<GEMM_GRID, 256, 0, stream>>>(out, W2, b2, t, s_sliced);
    // 7) gather+GN layer-2
    gather_gn_kernel<<<gather_grid, 256, 0, stream>>>(s_sliced, rowptr, eid, gamma2, beta2, out, N_NODES);
}